// Round 1
// baseline (143.260 us; speedup 1.0000x reference)
//
#include <hip/hip_runtime.h>
#include <math.h>

// CapLayer: grouped 1x1 conv + dynamic routing (ROUTE_NUM=3), fully fused.
// One block per (batch, out_capsule) pair. pred[16][1152] lives in registers
// distributed across 384 threads (3 i-indices per thread, 48 regs).

#define G_      32
#define IND_    8
#define J_      10
#define D_      16
#define S_      36            // H*W = 6*6
#define ITOT_   (G_ * S_)     // 1152
#define NT_     384
#define QN_     3             // ITOT_ / NT_
#define NW_     (NT_ / 64)    // 6 waves

__global__ __launch_bounds__(NT_) void caps_route_kernel(
    const float* __restrict__ x,     // (256, 256, 36) = (b, g*8+id, s)
    const float* __restrict__ Wt,    // (32, 160, 8)   = (g, j*16+d, id)
    const float* __restrict__ bias,  // (5120,)        = g*160 + j*16 + d
    float* __restrict__ out)         // (256, 10, 16)
{
    const int bj   = blockIdx.x;
    const int b    = bj / J_;
    const int j    = bj % J_;
    const int t    = threadIdx.x;
    const int lane = t & 63;
    const int wid  = t >> 6;

    __shared__ __align__(16) float xs[G_ * IND_ * S_];   // 9216 f = 36 KB
    __shared__ __align__(16) float Ws[G_ * D_ * IND_];   // 4096 f = 16 KB (g,d,id)
    __shared__ float bs_[G_ * D_];                       // 512 f
    __shared__ float red[NW_][D_];
    __shared__ float sv[D_];
    __shared__ float scal[2];

    // ---- stage x[b] into LDS (coalesced float4) ----
    {
        const float4* src = (const float4*)(x + (size_t)b * (G_ * IND_ * S_));
        float4* dst = (float4*)xs;
        #pragma unroll
        for (int idx = t; idx < (G_ * IND_ * S_) / 4; idx += NT_) dst[idx] = src[idx];
    }
    // ---- stage W j-slice: per group, 128 contiguous floats at g*1280 + j*128 ----
    for (int idx = t; idx < (G_ * D_ * IND_) / 4; idx += NT_) {
        int g = idx >> 5;      // 32 float4 per group
        int r = idx & 31;
        ((float4*)Ws)[idx] =
            *(const float4*)(Wt + (size_t)g * (J_ * D_ * IND_) + j * (D_ * IND_) + r * 4);
    }
    // ---- stage bias slice ----
    for (int idx = t; idx < G_ * D_; idx += NT_) {
        int g = idx >> 4;
        int d = idx & 15;
        bs_[idx] = bias[g * (J_ * D_) + j * D_ + d];
    }
    __syncthreads();

    // ---- compute pred[d][q] for i = t + q*NT_ (registers, static indexing) ----
    float pred[D_][QN_];
    #pragma unroll
    for (int q = 0; q < QN_; ++q) {
        const int i = t + q * NT_;
        const int g = i / S_;
        const int s = i - g * S_;
        const float* xp = xs + (g * IND_) * S_ + s;
        float xv[IND_];
        #pragma unroll
        for (int id = 0; id < IND_; ++id) xv[id] = xp[id * S_];
        const float4* wp = (const float4*)(Ws + g * (D_ * IND_));
        #pragma unroll
        for (int d = 0; d < D_; ++d) {
            float4 w0 = wp[d * 2 + 0];
            float4 w1 = wp[d * 2 + 1];
            float acc = bs_[g * D_ + d];
            acc += w0.x * xv[0] + w0.y * xv[1] + w0.z * xv[2] + w0.w * xv[3];
            acc += w1.x * xv[4] + w1.y * xv[5] + w1.z * xv[6] + w1.w * xv[7];
            pred[d][q] = acc;
        }
    }

    // ---- dynamic routing (3 iters), logits b_loc in registers ----
    float b_loc[QN_] = {0.f, 0.f, 0.f};
    float v[D_];
    const float EPS = 2.220446049250313e-16f;  // np.finfo(float64).eps

    #pragma unroll 1
    for (int it = 0; it < 3; ++it) {
        float c[QN_];
        if (it == 0) {
            const float inv = 1.0f / (float)ITOT_;
            #pragma unroll
            for (int q = 0; q < QN_; ++q) c[q] = inv;
        } else {
            // block softmax over the 1152 i's
            float m = fmaxf(fmaxf(b_loc[0], b_loc[1]), b_loc[2]);
            #pragma unroll
            for (int off = 32; off >= 1; off >>= 1) m = fmaxf(m, __shfl_xor(m, off));
            if (lane == 0) red[wid][0] = m;
            __syncthreads();
            if (t == 0) {
                float mm = red[0][0];
                for (int w = 1; w < NW_; ++w) mm = fmaxf(mm, red[w][0]);
                scal[0] = mm;
            }
            __syncthreads();
            m = scal[0];
            float e[QN_], se = 0.f;
            #pragma unroll
            for (int q = 0; q < QN_; ++q) { e[q] = __expf(b_loc[q] - m); se += e[q]; }
            #pragma unroll
            for (int off = 32; off >= 1; off >>= 1) se += __shfl_xor(se, off);
            if (lane == 0) red[wid][1] = se;
            __syncthreads();
            if (t == 0) {
                float ss = 0.f;
                for (int w = 0; w < NW_; ++w) ss += red[w][1];
                scal[1] = ss;
            }
            __syncthreads();
            const float inv = 1.0f / scal[1];
            #pragma unroll
            for (int q = 0; q < QN_; ++q) c[q] = e[q] * inv;
        }

        // s[d] = sum_i pred[d][i] * c[i]  (wave shfl tree + cross-wave LDS)
        float part[D_];
        #pragma unroll
        for (int d = 0; d < D_; ++d) {
            float p = pred[d][0] * c[0] + pred[d][1] * c[1] + pred[d][2] * c[2];
            #pragma unroll
            for (int off = 32; off >= 1; off >>= 1) p += __shfl_xor(p, off);
            part[d] = p;
        }
        if (lane == 0) {
            #pragma unroll
            for (int d = 0; d < D_; ++d) red[wid][d] = part[d];
        }
        __syncthreads();
        if (t < D_) {
            float ss = 0.f;
            for (int w = 0; w < NW_; ++w) ss += red[w][t];
            sv[t] = ss;
        }
        __syncthreads();

        // squash (redundant per-thread; 16 broadcast values)
        float n2 = 0.f;
        #pragma unroll
        for (int d = 0; d < D_; ++d) { float z = sv[d]; n2 += z * z; }
        const float norm  = sqrtf(n2);
        const float coeff = (n2 / (1.f + n2)) / (norm + EPS);
        #pragma unroll
        for (int d = 0; d < D_; ++d) v[d] = sv[d] * coeff;

        if (it < 2) {
            #pragma unroll
            for (int q = 0; q < QN_; ++q) {
                float acc = 0.f;
                #pragma unroll
                for (int d = 0; d < D_; ++d) acc += v[d] * pred[d][q];
                b_loc[q] += acc;
            }
            __syncthreads();  // protect red/sv reuse next iteration
        }
    }

    if (t < D_) out[(size_t)bj * D_ + t] = v[t];
}

extern "C" void kernel_launch(void* const* d_in, const int* in_sizes, int n_in,
                              void* d_out, int out_size, void* d_ws, size_t ws_size,
                              hipStream_t stream) {
    const float* x    = (const float*)d_in[0];
    const float* Wt   = (const float*)d_in[1];
    const float* bias = (const float*)d_in[2];
    float* out        = (float*)d_out;

    const int bs = in_sizes[0] / (G_ * IND_ * S_);   // 256
    dim3 grid(bs * J_);
    dim3 block(NT_);
    caps_route_kernel<<<grid, block, 0, stream>>>(x, Wt, bias, out);
}

// Round 2
// 127.462 us; speedup vs baseline: 1.1239x; 1.1239x over previous
//
#include <hip/hip_runtime.h>
#include <math.h>

// CapLayer fused: grouped 1x1 conv + 3-iter dynamic routing.
// One block per (b, j). pred[16][3] in registers (48/thread).
// No x LDS staging (zero reuse) -> 19 KB LDS -> 4 blocks/CU.
// Softmax without max-sub (logits bounded by squash: |b| <~ 8).
// Un-normalized routing weights; denominator reduced in same barrier phase.

#define G_    32
#define IND_  8
#define J_    10
#define D_    16
#define S_    36
#define ITOT_ (G_ * S_)     // 1152
#define NT_   384
#define QN_   3
#define NW_   (NT_ / 64)    // 6

__global__ __launch_bounds__(NT_, 6) void caps_route_kernel(
    const float* __restrict__ x,     // (b, g*8+id, s)
    const float* __restrict__ Wt,    // (g, j*16+d, id)
    const float* __restrict__ bias,  // g*160 + j*16 + d
    float* __restrict__ out)         // (b, j, d)
{
    // XCD swizzle: all 10 j-blocks of one b land on the same XCD (L2 x-reuse)
    const int B = blockIdx.x;
    const int nwg = gridDim.x;
    const int bj = ((nwg & 7) == 0) ? (B & 7) * (nwg >> 3) + (B >> 3) : B;
    const int b = bj / J_;
    const int j = bj - b * J_;
    const int t = threadIdx.x;
    const int lane = t & 63;
    const int wid = t >> 6;

    __shared__ __align__(16) float Ws[G_ * D_ * IND_];   // 16 KB (g,d,id)
    __shared__ __align__(16) float bs_[G_ * D_];         // 2 KB
    __shared__ __align__(16) float pt[2][NW_][D_];       // per-wave s-partials
    __shared__ float sm[2][NW_];                         // per-wave exp-sums
    __shared__ __align__(16) float sv[2][D_];            // block s (unnormalized)

    // ---- preload this thread's 24 x values (overlaps W staging) ----
    float xv[QN_][IND_];
    int gq[QN_];
    const float* xb = x + (size_t)b * (G_ * IND_ * S_);
    #pragma unroll
    for (int q = 0; q < QN_; ++q) {
        const int i = t + q * NT_;
        const int g = i / S_;
        const int s = i - g * S_;
        gq[q] = g;
        const float* xp = xb + g * (IND_ * S_) + s;
        #pragma unroll
        for (int id = 0; id < IND_; ++id) xv[q][id] = xp[id * S_];
    }

    // ---- stage W j-slice (contiguous 128 floats per g) + bias ----
    for (int idx = t; idx < (G_ * D_ * IND_) / 4; idx += NT_) {
        const int g = idx >> 5, r = idx & 31;
        ((float4*)Ws)[idx] =
            *(const float4*)(Wt + (size_t)g * (J_ * D_ * IND_) + j * (D_ * IND_) + r * 4);
    }
    for (int idx = t; idx < G_ * D_; idx += NT_) {
        const int g = idx >> 4, d = idx & 15;
        bs_[idx] = bias[g * (J_ * D_) + j * D_ + d];
    }
    __syncthreads();

    // ---- pred[d][q] ----
    float pred[D_][QN_];
    #pragma unroll
    for (int q = 0; q < QN_; ++q) {
        const float4* wp = (const float4*)(Ws + gq[q] * (D_ * IND_));
        const float4* bp = (const float4*)(bs_ + gq[q] * D_);
        float4 bb0 = bp[0], bb1 = bp[1], bb2 = bp[2], bb3 = bp[3];
        const float* bbf = (const float*)&bb0;  // avoid dynamic idx; unroll below
        (void)bbf;
        #pragma unroll
        for (int d = 0; d < D_; ++d) {
            const float4 w0 = wp[d * 2 + 0];
            const float4 w1 = wp[d * 2 + 1];
            float bv;
            if (d < 4)       bv = (d == 0) ? bb0.x : (d == 1) ? bb0.y : (d == 2) ? bb0.z : bb0.w;
            else if (d < 8)  bv = (d == 4) ? bb1.x : (d == 5) ? bb1.y : (d == 6) ? bb1.z : bb1.w;
            else if (d < 12) bv = (d == 8) ? bb2.x : (d == 9) ? bb2.y : (d == 10) ? bb2.z : bb2.w;
            else             bv = (d == 12) ? bb3.x : (d == 13) ? bb3.y : (d == 14) ? bb3.z : bb3.w;
            pred[d][q] = bv
                + w0.x * xv[q][0] + w0.y * xv[q][1] + w0.z * xv[q][2] + w0.w * xv[q][3]
                + w1.x * xv[q][4] + w1.y * xv[q][5] + w1.z * xv[q][6] + w1.w * xv[q][7];
        }
    }

    // ---- routing ----
    float b_loc[QN_] = {0.f, 0.f, 0.f};
    const float EPS = 2.220446049250313e-16f;
    const int hib5 = lane & 32, hib4 = lane & 16, hib3 = lane & 8, hib2 = lane & 4;

    #pragma unroll 1
    for (int it = 0; it < 3; ++it) {
        const int k = it & 1;

        // un-normalized weights e[q] and their wave sum
        float e[QN_], se;
        if (it == 0) {
            e[0] = e[1] = e[2] = 1.f;
            se = 3.f;
        } else {
            se = 0.f;
            #pragma unroll
            for (int q = 0; q < QN_; ++q) { e[q] = __expf(b_loc[q]); se += e[q]; }
        }
        #pragma unroll
        for (int off = 32; off >= 1; off >>= 1) se += __shfl_xor(se, off);
        if (lane == 0) sm[k][wid] = se;

        // weighted per-thread partials
        float p[D_];
        #pragma unroll
        for (int d = 0; d < D_; ++d)
            p[d] = e[0] * pred[d][0] + e[1] * pred[d][1] + e[2] * pred[d][2];

        // packed butterfly: 16 values over 64 lanes, d-count halves per level
        float q8[8];
        #pragma unroll
        for (int dd = 0; dd < 8; ++dd) {
            const float tl = __shfl_xor(p[dd], 32);
            const float th = __shfl_xor(p[dd + 8], 32);
            q8[dd] = hib5 ? (p[dd + 8] + th) : (p[dd] + tl);
        }
        float q4[4];
        #pragma unroll
        for (int dd = 0; dd < 4; ++dd) {
            const float tl = __shfl_xor(q8[dd], 16);
            const float th = __shfl_xor(q8[dd + 4], 16);
            q4[dd] = hib4 ? (q8[dd + 4] + th) : (q8[dd] + tl);
        }
        float q2[2];
        #pragma unroll
        for (int dd = 0; dd < 2; ++dd) {
            const float tl = __shfl_xor(q2[0] = q4[dd], 8);  // dummy init avoided below
            (void)tl;
            q2[dd] = 0.f;
        }
        // (rewritten explicitly to keep SSA clean)
        {
            const float tl0 = __shfl_xor(q4[0], 8);
            const float th0 = __shfl_xor(q4[2], 8);
            q2[0] = hib3 ? (q4[2] + th0) : (q4[0] + tl0);
            const float tl1 = __shfl_xor(q4[1], 8);
            const float th1 = __shfl_xor(q4[3], 8);
            q2[1] = hib3 ? (q4[3] + th1) : (q4[1] + tl1);
        }
        float q1;
        {
            const float tl = __shfl_xor(q2[0], 4);
            const float th = __shfl_xor(q2[1], 4);
            q1 = hib2 ? (q2[1] + th) : (q2[0] + tl);
        }
        q1 += __shfl_xor(q1, 2);
        q1 += __shfl_xor(q1, 1);
        // lane l (l&3==0) holds wave-sum for d = l>>2
        if ((lane & 3) == 0) pt[k][wid][lane >> 2] = q1;
        __syncthreads();                                   // barrier A

        const float denom = sm[k][0] + sm[k][1] + sm[k][2] + sm[k][3] + sm[k][4] + sm[k][5];

        if (t < D_) {
            sv[k][t] = pt[k][0][t] + pt[k][1][t] + pt[k][2][t]
                     + pt[k][3][t] + pt[k][4][t] + pt[k][5][t];
        }
        __syncthreads();                                   // barrier B

        const float4 s0 = ((const float4*)sv[k])[0];
        const float4 s1 = ((const float4*)sv[k])[1];
        const float4 s2 = ((const float4*)sv[k])[2];
        const float4 s3 = ((const float4*)sv[k])[3];
        float ssq = s0.x * s0.x + s0.y * s0.y + s0.z * s0.z + s0.w * s0.w
                  + s1.x * s1.x + s1.y * s1.y + s1.z * s1.z + s1.w * s1.w
                  + s2.x * s2.x + s2.y * s2.y + s2.z * s2.z + s2.w * s2.w
                  + s3.x * s3.x + s3.y * s3.y + s3.z * s3.z + s3.w * s3.w;
        const float alpha = 1.0f / denom;
        const float n2 = ssq * alpha * alpha;
        const float norm = sqrtf(n2);
        const float coeff = (n2 / (1.f + n2)) / (norm + EPS);
        const float beta = alpha * coeff;   // v[d] = sv[d] * beta

        if (it < 2) {
            #pragma unroll
            for (int q = 0; q < QN_; ++q) {
                float dot =
                    s0.x * pred[0][q]  + s0.y * pred[1][q]  + s0.z * pred[2][q]  + s0.w * pred[3][q]
                  + s1.x * pred[4][q]  + s1.y * pred[5][q]  + s1.z * pred[6][q]  + s1.w * pred[7][q]
                  + s2.x * pred[8][q]  + s2.y * pred[9][q]  + s2.z * pred[10][q] + s2.w * pred[11][q]
                  + s3.x * pred[12][q] + s3.y * pred[13][q] + s3.z * pred[14][q] + s3.w * pred[15][q];
                b_loc[q] += beta * dot;
            }
        } else {
            if (t < D_) out[(size_t)bj * D_ + t] = sv[k][t] * beta;
        }
    }
}

extern "C" void kernel_launch(void* const* d_in, const int* in_sizes, int n_in,
                              void* d_out, int out_size, void* d_ws, size_t ws_size,
                              hipStream_t stream) {
    const float* x    = (const float*)d_in[0];
    const float* Wt   = (const float*)d_in[1];
    const float* bias = (const float*)d_in[2];
    float* out        = (float*)d_out;

    const int bs = in_sizes[0] / (G_ * IND_ * S_);   // 256
    dim3 grid(bs * J_);
    dim3 block(NT_);
    caps_route_kernel<<<grid, block, 0, stream>>>(x, Wt, bias, out);
}